// Round 5
// baseline (624.961 us; speedup 1.0000x reference)
//
#include <hip/hip_runtime.h>

typedef _Float16 f16;
typedef __attribute__((ext_vector_type(8))) _Float16 f16x8;
typedef __attribute__((ext_vector_type(4))) _Float16 f16x4;
typedef __attribute__((ext_vector_type(4))) float  f32x4;

#define B_    16384
#define N_    32
#define DIN_  128
#define DOUT_ 256

__device__ __forceinline__ float rdlane(float v, int lane) {
    return __uint_as_float(__builtin_amdgcn_readlane(__float_as_uint(v), lane));
}
__device__ __forceinline__ float red32(float v) {   // sum within each 32-lane half
    v += __shfl_xor(v, 1); v += __shfl_xor(v, 2); v += __shfl_xor(v, 4);
    v += __shfl_xor(v, 8); v += __shfl_xor(v, 16);
    return v;
}
// Chunk-local plane index (halves): row n (0..31) stride 136, col oc (0..127)
// XOR-swizzled on bits 3..5. Injective (136 > 127 max offset); preserves 4-half
// blocks (b64 writes) and 8-half blocks (b128 reads); keeps 8B/16B alignment.
__device__ __forceinline__ int xidx(int n, int oc) {
    return n * 136 + (oc ^ ((n & 7) << 3));
}

// Pack W (DIN x DOUT, fp32) into fp16 fragment order for mfma_f32_16x16x32_f16.
// Lane l holds elem [k = ks*32 + (l>>4)*8 + j][o = ot*16 + (l&15)], j=0..7.
// (A- and B-fragment lane patterns coincide, so this serves as the A operand.)
__global__ void prep_w(const float* __restrict__ W, f16* __restrict__ wp) {
    int tid = blockIdx.x * 256 + threadIdx.x;   // 0..4095
    int ks = tid >> 10;
    int ot = (tid >> 6) & 15;
    int l  = tid & 63;
    int k0 = ks * 32 + ((l >> 4) << 3);
    int o  = ot * 16 + (l & 15);
    f16 v[8];
#pragma unroll
    for (int j = 0; j < 8; ++j) v[j] = (f16)W[(size_t)(k0 + j) * DOUT_ + o];
    *reinterpret_cast<f16x8*>(&wp[(size_t)tid * 8]) = *reinterpret_cast<f16x8*>(v);
}

// LDS pool (bytes):
//   [0,     8704)   elds (P0/P1)  -- aliased by xh plane after P1
//   [8704,  17408)  xe plane
//   [17408, 22032)  glds (f32, 32 rows x stride 36 + 4)
//   [22032, 22160)  cpls[32]
//   [22160, 22164)  scls
// total 22164 -> 7 blocks/CU
#define XH_OFF_   0
#define XE_OFF_   8704
#define GLDS_OFF_ 17408
#define CPLS_OFF_ 22032

__global__ __launch_bounds__(256, 6) void dyr_main(
    const float* __restrict__ embeds, const float* __restrict__ weights,
    const f16* __restrict__ wp,       const float* __restrict__ bias,
    float* __restrict__ out)
{
    __shared__ __align__(16) char pool[22176];
    f16*   elds = reinterpret_cast<f16*>(pool);
    f16*   xh   = reinterpret_cast<f16*>(pool + XH_OFF_);   // aliases elds
    f16*   xe   = reinterpret_cast<f16*>(pool + XE_OFF_);
    float* glds = reinterpret_cast<float*>(pool + GLDS_OFF_);
    float* cpls = reinterpret_cast<float*>(pool + CPLS_OFF_);
    float* scls = cpls + 32;

    const int tid = threadIdx.x;
    const int w   = tid >> 6;      // wave 0..3 -> owns output cols [w*64, w*64+64)
    const int l   = tid & 63;
    const int col = l & 15;
    const int q   = l >> 4;        // quad within wave
    const int b   = blockIdx.x;
    const int n0  = l & 31;        // routing row for wave 0

    // issue the routing-logit load early (wave 0 consumes it much later)
    float bval = (w == 0) ? weights[(size_t)b * N_ + n0] : 0.f;

    // ---- P0: stage embeds[b] (32x128 fp32) -> f16 LDS ----
    const float4* e4 = reinterpret_cast<const float4*>(embeds + (size_t)b * N_ * DIN_);
#pragma unroll
    for (int p = 0; p < 4; ++p) {
        int fi = p * 256 + tid;            // float4 index, 32 per row
        float4 v = e4[fi];
        int m = fi >> 5;
        int k = (fi & 31) << 2;
        f16 pk[4] = { (f16)v.x, (f16)v.y, (f16)v.z, (f16)v.w };
        *reinterpret_cast<f16x4*>(&elds[m * 136 + k]) = *reinterpret_cast<f16x4*>(pk);
    }
    __syncthreads();

    // ---- P1: transposed GEMM. acc[ot][nt][r] = x[n = nt*16+col][o = w*64+ot*16+q*4+r]
    // Same loads as the row-major version; operands swapped (W is A, embeds is B).
    f32x4 acc[4][2];
#pragma unroll
    for (int ot = 0; ot < 4; ++ot)
#pragma unroll
        for (int nt = 0; nt < 2; ++nt) acc[ot][nt] = (f32x4){0.f, 0.f, 0.f, 0.f};

    const int boff0 = col * 136 + (q << 3);   // B-frag: n=col(+16*nt), k=q*8(+32*ks)
#pragma unroll
    for (int ks = 0; ks < 4; ++ks) {
        f16x8 b0 = *reinterpret_cast<const f16x8*>(&elds[boff0 + ks * 32]);
        f16x8 b1 = *reinterpret_cast<const f16x8*>(&elds[boff0 + 16 * 136 + ks * 32]);
#pragma unroll
        for (int ot = 0; ot < 4; ++ot) {
            f16x8 wf = *reinterpret_cast<const f16x8*>(
                &wp[((size_t)((ks * 16) + (w * 4 + ot)) * 64 + l) * 8]);
            acc[ot][0] = __builtin_amdgcn_mfma_f32_16x16x32_f16(wf, b0, acc[ot][0], 0, 0, 0);
            acc[ot][1] = __builtin_amdgcn_mfma_f32_16x16x32_f16(wf, b1, acc[ot][1], 0, 0, 0);
        }
    }
    // bias: o = w*64 + ot*16 + q*4 + r  -> one float4 per ot
#pragma unroll
    for (int ot = 0; ot < 4; ++ot) {
        f32x4 bb = *reinterpret_cast<const f32x4*>(&bias[w * 64 + ot * 16 + (q << 2)]);
#pragma unroll
        for (int nt = 0; nt < 2; ++nt)
#pragma unroll
            for (int r = 0; r < 4; ++r) acc[ot][nt][r] += bb[r];
    }
    __syncthreads();   // elds dead; planes may overwrite

    // ---- P2/P3: chunked split-fp16 Gram. G = X X^T, o-chunks of 128. ----
    const int mi = w >> 1, ni = w & 1;
    f32x4 gacc = (f32x4){0.f, 0.f, 0.f, 0.f};
#pragma unroll
    for (int c = 0; c < 2; ++c) {
        if ((w >> 1) == c) {
            // spill this wave's 64 o-columns: b64 per (ot,nt,plane)
#pragma unroll
            for (int ot = 0; ot < 4; ++ot)
#pragma unroll
                for (int nt = 0; nt < 2; ++nt) {
                    int n  = nt * 16 + col;
                    int oc = (w & 1) * 64 + ot * 16 + (q << 2);
                    f16 hv[4], ev[4];
#pragma unroll
                    for (int r = 0; r < 4; ++r) {
                        float xv = acc[ot][nt][r];
                        hv[r] = (f16)xv;
                        ev[r] = (f16)(xv - (float)hv[r]);
                    }
                    int idx = xidx(n, oc);
                    *reinterpret_cast<f16x4*>(&xh[idx]) = *reinterpret_cast<f16x4*>(hv);
                    *reinterpret_cast<f16x4*>(&xe[idx]) = *reinterpret_cast<f16x4*>(ev);
                }
        }
        __syncthreads();
        // Gram partial over this chunk; wave w owns G tile (mi,ni).
#pragma unroll
        for (int ks = 0; ks < 4; ++ks) {
            int ra = xidx(mi * 16 + col, ks * 32 + (q << 3));
            f16x8 ha = *reinterpret_cast<const f16x8*>(&xh[ra]);
            f16x8 ea = *reinterpret_cast<const f16x8*>(&xe[ra]);
            f16x8 hb = ha, eb = ea;
            if (mi != ni) {
                int rb = xidx(ni * 16 + col, ks * 32 + (q << 3));
                hb = *reinterpret_cast<const f16x8*>(&xh[rb]);
                eb = *reinterpret_cast<const f16x8*>(&xe[rb]);
            }
            gacc = __builtin_amdgcn_mfma_f32_16x16x32_f16(ha, hb, gacc, 0, 0, 0);
            gacc = __builtin_amdgcn_mfma_f32_16x16x32_f16(ha, eb, gacc, 0, 0, 0);
            gacc = __builtin_amdgcn_mfma_f32_16x16x32_f16(ea, hb, gacc, 0, 0, 0);
        }
        if (c == 0) __syncthreads();   // reads done before round-1 overwrites
    }
#pragma unroll
    for (int r = 0; r < 4; ++r)
        glds[(mi * 16 + q * 4 + r) * 36 + ni * 16 + col] = gacc[r];
    __syncthreads();

    // ---- P4: wave 0 does ALL routing on the 32x32 Gram matrix ----
    float cval = 0.f, scale = 0.f, rn = 0.f;
    if (w == 0) {
        float dv = glds[n0 * 36 + n0];
        rn = rsqrtf(fmaxf(dv, 1e-24f));

        float g[32];
#pragma unroll
        for (int j8 = 0; j8 < 8; ++j8) {
            f32x4 gv = *reinterpret_cast<const f32x4*>(&glds[n0 * 36 + j8 * 4]);
#pragma unroll
            for (int r = 0; r < 4; ++r) g[j8 * 4 + r] = gv[r] * rn;
        }
#pragma unroll
        for (int j = 0; j < 32; ++j) g[j] *= rdlane(rn, j);

        for (int it = 0; it < 3; ++it) {
            float mx = bval;
            mx = fmaxf(mx, __shfl_xor(mx, 1));  mx = fmaxf(mx, __shfl_xor(mx, 2));
            mx = fmaxf(mx, __shfl_xor(mx, 4));  mx = fmaxf(mx, __shfl_xor(mx, 8));
            mx = fmaxf(mx, __shfl_xor(mx, 16));
            float ex = __expf(bval - mx);
            float sm = red32(ex);
            cval = ex * (32.0f / sm);
            float t0 = 0.f, t1 = 0.f;
#pragma unroll
            for (int j = 0; j < 32; j += 2) {
                t0 = fmaf(g[j],     rdlane(cval, j),     t0);
                t1 = fmaf(g[j + 1], rdlane(cval, j + 1), t1);
            }
            float t = t0 + t1;
            float sq = red32(cval * t);
            scale = sq / ((1.0f + sq) * sqrtf(sq + 1e-9f));
            if (it < 2) bval = fmaf(scale, t, bval);
        }

        if (l < 32) {
            cpls[l] = cval * rn;                                   // c'_n = c_n * rn_n
            out[(size_t)B_ * DOUT_ + (size_t)b * N_ + l] = cval;   // c_out
        }
        if (l == 0) *scls = scale;
    }
    __syncthreads();

    // ---- P6: s_o = sum_n c'_n x[n][o]; multi-value butterfly over the 16-col group.
    {
        float sc = *scls;
        float c0 = cpls[col];
        float c1 = cpls[16 + col];
        float cur[16];
#pragma unroll
        for (int ot = 0; ot < 4; ++ot)
#pragma unroll
            for (int r = 0; r < 4; ++r)
                cur[ot * 4 + r] = fmaf(c0, acc[ot][0][r], c1 * acc[ot][1][r]);

        // 4-stage butterfly: lane col ends with value index v == col,
        // summed over its 16-lane group. Static indices throughout.
        float k8[8], s8[8];
        {
            const bool hi = (col & 8) != 0;
#pragma unroll
            for (int i = 0; i < 8; ++i) {
                k8[i] = hi ? cur[i + 8] : cur[i];
                s8[i] = hi ? cur[i] : cur[i + 8];
            }
#pragma unroll
            for (int i = 0; i < 8; ++i) k8[i] += __shfl_xor(s8[i], 8);
        }
        float k4[4], s4[4];
        {
            const bool hi = (col & 4) != 0;
#pragma unroll
            for (int i = 0; i < 4; ++i) {
                k4[i] = hi ? k8[i + 4] : k8[i];
                s4[i] = hi ? k8[i] : k8[i + 4];
            }
#pragma unroll
            for (int i = 0; i < 4; ++i) k4[i] += __shfl_xor(s4[i], 4);
        }
        float k2[2], s2[2];
        {
            const bool hi = (col & 2) != 0;
#pragma unroll
            for (int i = 0; i < 2; ++i) {
                k2[i] = hi ? k4[i + 2] : k4[i];
                s2[i] = hi ? k4[i] : k4[i + 2];
            }
#pragma unroll
            for (int i = 0; i < 2; ++i) k2[i] += __shfl_xor(s2[i], 2);
        }
        float k1, s1;
        {
            const bool hi = (col & 1) != 0;
            k1 = hi ? k2[1] : k2[0];
            s1 = hi ? k2[0] : k2[1];
            k1 += __shfl_xor(s1, 1);
        }
        // lane (q,col) holds s[o], o = w*64 + (col>>2)*16 + q*4 + (col&3)
        int o = (col >> 2) * 16 + (q << 2) + (col & 3);
        out[(size_t)b * DOUT_ + w * 64 + o] = sc * k1;
    }
}

extern "C" void kernel_launch(void* const* d_in, const int* in_sizes, int n_in,
                              void* d_out, int out_size, void* d_ws, size_t ws_size,
                              hipStream_t stream) {
    const float* embeds  = (const float*)d_in[0];
    const float* weights = (const float*)d_in[1];
    const float* W       = (const float*)d_in[2];
    const float* bias    = (const float*)d_in[3];
    float* out = (float*)d_out;
    f16* wp = (f16*)d_ws;    // 64 KB of packed fp16 W

    prep_w<<<16, 256, 0, stream>>>(W, wp);
    dyr_main<<<B_, 256, 0, stream>>>(embeds, weights, wp, bias, out);
}

// Round 6
// 506.390 us; speedup vs baseline: 1.2342x; 1.2342x over previous
//
#include <hip/hip_runtime.h>

typedef _Float16 f16;
typedef __attribute__((ext_vector_type(8))) _Float16 f16x8;
typedef __attribute__((ext_vector_type(4))) _Float16 f16x4;
typedef __attribute__((ext_vector_type(4))) float  f32x4;

#define B_    16384
#define N_    32
#define DIN_  128
#define DOUT_ 256

__device__ __forceinline__ float rdlane(float v, int lane) {
    return __uint_as_float(__builtin_amdgcn_readlane(__float_as_uint(v), lane));
}
__device__ __forceinline__ float red32(float v) {   // sum within each 32-lane half
    v += __shfl_xor(v, 1); v += __shfl_xor(v, 2); v += __shfl_xor(v, 4);
    v += __shfl_xor(v, 8); v += __shfl_xor(v, 16);
    return v;
}
// Chunk-local plane index (halves): row n (0..31) stride 136, col oc (0..127)
// XOR-swizzled on bits 3..5. Injective (136 > 127 max offset); preserves 4-half
// blocks (b64 writes) and 8-half blocks (b128 reads); keeps 8B/16B alignment.
__device__ __forceinline__ int xidx(int n, int oc) {
    return n * 136 + (oc ^ ((n & 7) << 3));
}

// Pack W (DIN x DOUT, fp32) into fp16 fragment order for mfma_f32_16x16x32_f16.
// Lane l holds elem [k = ks*32 + (l>>4)*8 + j][o = ot*16 + (l&15)], j=0..7.
// (A- and B-fragment lane patterns coincide, so this serves as the A operand.)
__global__ void prep_w(const float* __restrict__ W, f16* __restrict__ wp) {
    int tid = blockIdx.x * 256 + threadIdx.x;   // 0..4095
    int ks = tid >> 10;
    int ot = (tid >> 6) & 15;
    int l  = tid & 63;
    int k0 = ks * 32 + ((l >> 4) << 3);
    int o  = ot * 16 + (l & 15);
    f16 v[8];
#pragma unroll
    for (int j = 0; j < 8; ++j) v[j] = (f16)W[(size_t)(k0 + j) * DOUT_ + o];
    *reinterpret_cast<f16x8*>(&wp[(size_t)tid * 8]) = *reinterpret_cast<f16x8*>(v);
}

// LDS pool (bytes):
//   [0,     8704)   elds (P0/P1)  -- aliased by xh plane after P1
//   [8704,  17408)  xe plane
//   [17408, 22032)  glds (f32, 32 rows x stride 36 + 4)
//   [22032, 22160)  cpls[32]
//   [22160, 22164)  scls
// total 22164 -> LDS allows 7 blocks/CU
#define XH_OFF_   0
#define XE_OFF_   8704
#define GLDS_OFF_ 17408
#define CPLS_OFF_ 22032

// NOTE: min-waves/EU stays at 4 (VGPR cap 128). Declaring 6 here caps the
// allocator at ~85 VGPR and spills ~30 regs/thread to scratch: round-5 showed
// WRITE_SIZE 18 MB -> 494 MB and dur 178 -> 370 us. Do not raise this.
__global__ __launch_bounds__(256, 4) void dyr_main(
    const float* __restrict__ embeds, const float* __restrict__ weights,
    const f16* __restrict__ wp,       const float* __restrict__ bias,
    float* __restrict__ out)
{
    __shared__ __align__(16) char pool[22176];
    f16*   elds = reinterpret_cast<f16*>(pool);
    f16*   xh   = reinterpret_cast<f16*>(pool + XH_OFF_);   // aliases elds
    f16*   xe   = reinterpret_cast<f16*>(pool + XE_OFF_);
    float* glds = reinterpret_cast<float*>(pool + GLDS_OFF_);
    float* cpls = reinterpret_cast<float*>(pool + CPLS_OFF_);
    float* scls = cpls + 32;

    const int tid = threadIdx.x;
    const int w   = tid >> 6;      // wave 0..3 -> owns output cols [w*64, w*64+64)
    const int l   = tid & 63;
    const int col = l & 15;
    const int q   = l >> 4;        // quad within wave
    const int b   = blockIdx.x;
    const int n0  = l & 31;        // routing row for wave 0

    // issue the routing-logit load early (wave 0 consumes it much later)
    float bval = (w == 0) ? weights[(size_t)b * N_ + n0] : 0.f;

    // ---- P0: stage embeds[b] (32x128 fp32) -> f16 LDS ----
    const float4* e4 = reinterpret_cast<const float4*>(embeds + (size_t)b * N_ * DIN_);
#pragma unroll
    for (int p = 0; p < 4; ++p) {
        int fi = p * 256 + tid;            // float4 index, 32 per row
        float4 v = e4[fi];
        int m = fi >> 5;
        int k = (fi & 31) << 2;
        f16 pk[4] = { (f16)v.x, (f16)v.y, (f16)v.z, (f16)v.w };
        *reinterpret_cast<f16x4*>(&elds[m * 136 + k]) = *reinterpret_cast<f16x4*>(pk);
    }
    __syncthreads();

    // ---- P1: transposed GEMM. acc[ot][nt][r] = x[n = nt*16+col][o = w*64+ot*16+q*4+r]
    // Same loads as the row-major version; operands swapped (W is A, embeds is B).
    f32x4 acc[4][2];
#pragma unroll
    for (int ot = 0; ot < 4; ++ot)
#pragma unroll
        for (int nt = 0; nt < 2; ++nt) acc[ot][nt] = (f32x4){0.f, 0.f, 0.f, 0.f};

    const int boff0 = col * 136 + (q << 3);   // B-frag: n=col(+16*nt), k=q*8(+32*ks)
#pragma unroll
    for (int ks = 0; ks < 4; ++ks) {
        f16x8 b0 = *reinterpret_cast<const f16x8*>(&elds[boff0 + ks * 32]);
        f16x8 b1 = *reinterpret_cast<const f16x8*>(&elds[boff0 + 16 * 136 + ks * 32]);
#pragma unroll
        for (int ot = 0; ot < 4; ++ot) {
            f16x8 wf = *reinterpret_cast<const f16x8*>(
                &wp[((size_t)((ks * 16) + (w * 4 + ot)) * 64 + l) * 8]);
            acc[ot][0] = __builtin_amdgcn_mfma_f32_16x16x32_f16(wf, b0, acc[ot][0], 0, 0, 0);
            acc[ot][1] = __builtin_amdgcn_mfma_f32_16x16x32_f16(wf, b1, acc[ot][1], 0, 0, 0);
        }
    }
    // bias: o = w*64 + ot*16 + q*4 + r  -> one float4 per ot
#pragma unroll
    for (int ot = 0; ot < 4; ++ot) {
        f32x4 bb = *reinterpret_cast<const f32x4*>(&bias[w * 64 + ot * 16 + (q << 2)]);
#pragma unroll
        for (int nt = 0; nt < 2; ++nt)
#pragma unroll
            for (int r = 0; r < 4; ++r) acc[ot][nt][r] += bb[r];
    }
    __syncthreads();   // elds dead; planes may overwrite

    // ---- P2/P3: chunked split-fp16 Gram. G = X X^T, o-chunks of 128. ----
    const int mi = w >> 1, ni = w & 1;
    f32x4 gacc = (f32x4){0.f, 0.f, 0.f, 0.f};
#pragma unroll
    for (int c = 0; c < 2; ++c) {
        if ((w >> 1) == c) {
            // spill this wave's 64 o-columns: b64 per (ot,nt,plane)
#pragma unroll
            for (int ot = 0; ot < 4; ++ot)
#pragma unroll
                for (int nt = 0; nt < 2; ++nt) {
                    int n  = nt * 16 + col;
                    int oc = (w & 1) * 64 + ot * 16 + (q << 2);
                    f16 hv[4], ev[4];
#pragma unroll
                    for (int r = 0; r < 4; ++r) {
                        float xv = acc[ot][nt][r];
                        hv[r] = (f16)xv;
                        ev[r] = (f16)(xv - (float)hv[r]);
                    }
                    int idx = xidx(n, oc);
                    *reinterpret_cast<f16x4*>(&xh[idx]) = *reinterpret_cast<f16x4*>(hv);
                    *reinterpret_cast<f16x4*>(&xe[idx]) = *reinterpret_cast<f16x4*>(ev);
                }
        }
        __syncthreads();
        // Gram partial over this chunk; wave w owns G tile (mi,ni).
#pragma unroll
        for (int ks = 0; ks < 4; ++ks) {
            int ra = xidx(mi * 16 + col, ks * 32 + (q << 3));
            f16x8 ha = *reinterpret_cast<const f16x8*>(&xh[ra]);
            f16x8 ea = *reinterpret_cast<const f16x8*>(&xe[ra]);
            f16x8 hb = ha, eb = ea;
            if (mi != ni) {
                int rb = xidx(ni * 16 + col, ks * 32 + (q << 3));
                hb = *reinterpret_cast<const f16x8*>(&xh[rb]);
                eb = *reinterpret_cast<const f16x8*>(&xe[rb]);
            }
            gacc = __builtin_amdgcn_mfma_f32_16x16x32_f16(ha, hb, gacc, 0, 0, 0);
            gacc = __builtin_amdgcn_mfma_f32_16x16x32_f16(ha, eb, gacc, 0, 0, 0);
            gacc = __builtin_amdgcn_mfma_f32_16x16x32_f16(ea, hb, gacc, 0, 0, 0);
        }
        if (c == 0) __syncthreads();   // reads done before round-1 overwrites
    }
#pragma unroll
    for (int r = 0; r < 4; ++r)
        glds[(mi * 16 + q * 4 + r) * 36 + ni * 16 + col] = gacc[r];
    __syncthreads();

    // ---- P4: wave 0 does ALL routing on the 32x32 Gram matrix ----
    float cval = 0.f, scale = 0.f, rn = 0.f;
    if (w == 0) {
        float dv = glds[n0 * 36 + n0];
        rn = rsqrtf(fmaxf(dv, 1e-24f));

        float g[32];
#pragma unroll
        for (int j8 = 0; j8 < 8; ++j8) {
            f32x4 gv = *reinterpret_cast<const f32x4*>(&glds[n0 * 36 + j8 * 4]);
#pragma unroll
            for (int r = 0; r < 4; ++r) g[j8 * 4 + r] = gv[r] * rn;
        }
#pragma unroll
        for (int j = 0; j < 32; ++j) g[j] *= rdlane(rn, j);

        for (int it = 0; it < 3; ++it) {
            float mx = bval;
            mx = fmaxf(mx, __shfl_xor(mx, 1));  mx = fmaxf(mx, __shfl_xor(mx, 2));
            mx = fmaxf(mx, __shfl_xor(mx, 4));  mx = fmaxf(mx, __shfl_xor(mx, 8));
            mx = fmaxf(mx, __shfl_xor(mx, 16));
            float ex = __expf(bval - mx);
            float sm = red32(ex);
            cval = ex * (32.0f / sm);
            float t0 = 0.f, t1 = 0.f;
#pragma unroll
            for (int j = 0; j < 32; j += 2) {
                t0 = fmaf(g[j],     rdlane(cval, j),     t0);
                t1 = fmaf(g[j + 1], rdlane(cval, j + 1), t1);
            }
            float t = t0 + t1;
            float sq = red32(cval * t);
            scale = sq / ((1.0f + sq) * sqrtf(sq + 1e-9f));
            if (it < 2) bval = fmaf(scale, t, bval);
        }

        if (l < 32) {
            cpls[l] = cval * rn;                                   // c'_n = c_n * rn_n
            out[(size_t)B_ * DOUT_ + (size_t)b * N_ + l] = cval;   // c_out
        }
        if (l == 0) *scls = scale;
    }
    __syncthreads();

    // ---- P6: s_o = sum_n c'_n x[n][o]; multi-value butterfly over the 16-col group.
    {
        float sc = *scls;
        float c0 = cpls[col];
        float c1 = cpls[16 + col];
        float cur[16];
#pragma unroll
        for (int ot = 0; ot < 4; ++ot)
#pragma unroll
            for (int r = 0; r < 4; ++r)
                cur[ot * 4 + r] = fmaf(c0, acc[ot][0][r], c1 * acc[ot][1][r]);

        // 4-stage butterfly: lane col ends with value index v == col,
        // summed over its 16-lane group. Static indices throughout.
        float k8[8], s8[8];
        {
            const bool hi = (col & 8) != 0;
#pragma unroll
            for (int i = 0; i < 8; ++i) {
                k8[i] = hi ? cur[i + 8] : cur[i];
                s8[i] = hi ? cur[i] : cur[i + 8];
            }
#pragma unroll
            for (int i = 0; i < 8; ++i) k8[i] += __shfl_xor(s8[i], 8);
        }
        float k4[4], s4[4];
        {
            const bool hi = (col & 4) != 0;
#pragma unroll
            for (int i = 0; i < 4; ++i) {
                k4[i] = hi ? k8[i + 4] : k8[i];
                s4[i] = hi ? k8[i] : k8[i + 4];
            }
#pragma unroll
            for (int i = 0; i < 4; ++i) k4[i] += __shfl_xor(s4[i], 4);
        }
        float k2[2], s2[2];
        {
            const bool hi = (col & 2) != 0;
#pragma unroll
            for (int i = 0; i < 2; ++i) {
                k2[i] = hi ? k4[i + 2] : k4[i];
                s2[i] = hi ? k4[i] : k4[i + 2];
            }
#pragma unroll
            for (int i = 0; i < 2; ++i) k2[i] += __shfl_xor(s2[i], 2);
        }
        float k1, s1;
        {
            const bool hi = (col & 1) != 0;
            k1 = hi ? k2[1] : k2[0];
            s1 = hi ? k2[0] : k2[1];
            k1 += __shfl_xor(s1, 1);
        }
        // lane (q,col) holds s[o], o = w*64 + (col>>2)*16 + q*4 + (col&3)
        int o = (col >> 2) * 16 + (q << 2) + (col & 3);
        out[(size_t)b * DOUT_ + w * 64 + o] = sc * k1;
    }
}

extern "C" void kernel_launch(void* const* d_in, const int* in_sizes, int n_in,
                              void* d_out, int out_size, void* d_ws, size_t ws_size,
                              hipStream_t stream) {
    const float* embeds  = (const float*)d_in[0];
    const float* weights = (const float*)d_in[1];
    const float* W       = (const float*)d_in[2];
    const float* bias    = (const float*)d_in[3];
    float* out = (float*)d_out;
    f16* wp = (f16*)d_ws;    // 64 KB of packed fp16 W

    prep_w<<<16, 256, 0, stream>>>(W, wp);
    dyr_main<<<B_, 256, 0, stream>>>(embeds, weights, wp, bias, out);
}

// Round 7
// 447.790 us; speedup vs baseline: 1.3957x; 1.1309x over previous
//
#include <hip/hip_runtime.h>

typedef _Float16 f16;
typedef __attribute__((ext_vector_type(8))) _Float16 f16x8;
typedef __attribute__((ext_vector_type(4))) _Float16 f16x4;
typedef __attribute__((ext_vector_type(4))) float  f32x4;

#define B_    16384
#define N_    32
#define DIN_  128
#define DOUT_ 256

__device__ __forceinline__ float rdlane(float v, int lane) {
    return __uint_as_float(__builtin_amdgcn_readlane(__float_as_uint(v), lane));
}
__device__ __forceinline__ float red32(float v) {   // sum within each 32-lane half
    v += __shfl_xor(v, 1); v += __shfl_xor(v, 2); v += __shfl_xor(v, 4);
    v += __shfl_xor(v, 8); v += __shfl_xor(v, 16);
    return v;
}
// Chunk-local plane index (halves): row n (0..31) stride 136, col oc (0..127).
// LINEAR — no XOR swizzle. With stride 136 both hot patterns are bank-minimal:
//   Gram b128 read (n=mi*16+col, oc=ks*32+8q): group=(col+q)%8 -> 8 lanes/group (free)
//   spill b64 write (n=nt*16+col, oc=+16ot+4q): pair=(2col+q+4ot)%16 -> 4 lanes/pair (min)
// Round-6's XOR swizzle piled 16 lanes on one group (8-way): 57.7M conflicts. Do not re-add.
__device__ __forceinline__ int xidx(int n, int oc) {
    return n * 136 + oc;
}

// Pack W (DIN x DOUT, fp32) into fp16 fragment order for mfma_f32_16x16x32_f16.
// Lane l holds elem [k = ks*32 + (l>>4)*8 + j][o = ot*16 + (l&15)], j=0..7.
// (A- and B-fragment lane patterns coincide, so this serves as the A operand.)
__global__ void prep_w(const float* __restrict__ W, f16* __restrict__ wp) {
    int tid = blockIdx.x * 256 + threadIdx.x;   // 0..4095
    int ks = tid >> 10;
    int ot = (tid >> 6) & 15;
    int l  = tid & 63;
    int k0 = ks * 32 + ((l >> 4) << 3);
    int o  = ot * 16 + (l & 15);
    f16 v[8];
#pragma unroll
    for (int j = 0; j < 8; ++j) v[j] = (f16)W[(size_t)(k0 + j) * DOUT_ + o];
    *reinterpret_cast<f16x8*>(&wp[(size_t)tid * 8]) = *reinterpret_cast<f16x8*>(v);
}

// LDS pool (bytes):
//   [0,     8704)   elds (P0/P1)  -- aliased by xh plane after P1
//   [8704,  17408)  xe plane
//   [17408, 22032)  glds (f32, 32 rows x stride 36 + 4)
//   [22032, 22160)  cpls[32]
//   [22160, 22164)  scls
// total 22164 -> LDS allows 7 blocks/CU
#define XH_OFF_   0
#define XE_OFF_   8704
#define GLDS_OFF_ 17408
#define CPLS_OFF_ 22032

// NOTE: min-waves/EU stays at 4 (VGPR cap 128). Declaring 6 here caps the
// allocator at ~85 VGPR and spills ~30 regs/thread to scratch: round-5 showed
// WRITE_SIZE 18 MB -> 494 MB and dur 178 -> 370 us. Do not raise this.
__global__ __launch_bounds__(256, 4) void dyr_main(
    const float* __restrict__ embeds, const float* __restrict__ weights,
    const f16* __restrict__ wp,       const float* __restrict__ bias,
    float* __restrict__ out)
{
    __shared__ __align__(16) char pool[22176];
    f16*   elds = reinterpret_cast<f16*>(pool);
    f16*   xh   = reinterpret_cast<f16*>(pool + XH_OFF_);   // aliases elds
    f16*   xe   = reinterpret_cast<f16*>(pool + XE_OFF_);
    float* glds = reinterpret_cast<float*>(pool + GLDS_OFF_);
    float* cpls = reinterpret_cast<float*>(pool + CPLS_OFF_);
    float* scls = cpls + 32;

    const int tid = threadIdx.x;
    const int w   = tid >> 6;      // wave 0..3 -> owns output cols [w*64, w*64+64)
    const int l   = tid & 63;
    const int col = l & 15;
    const int q   = l >> 4;        // quad within wave
    const int b   = blockIdx.x;
    const int n0  = l & 31;        // routing row for wave 0

    // issue the routing-logit load early (wave 0 consumes it much later)
    float bval = (w == 0) ? weights[(size_t)b * N_ + n0] : 0.f;

    // ---- P0: stage embeds[b] (32x128 fp32) -> f16 LDS ----
    const float4* e4 = reinterpret_cast<const float4*>(embeds + (size_t)b * N_ * DIN_);
#pragma unroll
    for (int p = 0; p < 4; ++p) {
        int fi = p * 256 + tid;            // float4 index, 32 per row
        float4 v = e4[fi];
        int m = fi >> 5;
        int k = (fi & 31) << 2;
        f16 pk[4] = { (f16)v.x, (f16)v.y, (f16)v.z, (f16)v.w };
        *reinterpret_cast<f16x4*>(&elds[m * 136 + k]) = *reinterpret_cast<f16x4*>(pk);
    }
    __syncthreads();

    // ---- P1: transposed GEMM. acc[ot][nt][r] = x[n = nt*16+col][o = w*64+ot*16+q*4+r]
    // Same loads as the row-major version; operands swapped (W is A, embeds is B).
    f32x4 acc[4][2];
#pragma unroll
    for (int ot = 0; ot < 4; ++ot)
#pragma unroll
        for (int nt = 0; nt < 2; ++nt) acc[ot][nt] = (f32x4){0.f, 0.f, 0.f, 0.f};

    const int boff0 = col * 136 + (q << 3);   // B-frag: n=col(+16*nt), k=q*8(+32*ks)
#pragma unroll
    for (int ks = 0; ks < 4; ++ks) {
        f16x8 b0 = *reinterpret_cast<const f16x8*>(&elds[boff0 + ks * 32]);
        f16x8 b1 = *reinterpret_cast<const f16x8*>(&elds[boff0 + 16 * 136 + ks * 32]);
#pragma unroll
        for (int ot = 0; ot < 4; ++ot) {
            f16x8 wf = *reinterpret_cast<const f16x8*>(
                &wp[((size_t)((ks * 16) + (w * 4 + ot)) * 64 + l) * 8]);
            acc[ot][0] = __builtin_amdgcn_mfma_f32_16x16x32_f16(wf, b0, acc[ot][0], 0, 0, 0);
            acc[ot][1] = __builtin_amdgcn_mfma_f32_16x16x32_f16(wf, b1, acc[ot][1], 0, 0, 0);
        }
    }
    // bias: o = w*64 + ot*16 + q*4 + r  -> one float4 per ot
#pragma unroll
    for (int ot = 0; ot < 4; ++ot) {
        f32x4 bb = *reinterpret_cast<const f32x4*>(&bias[w * 64 + ot * 16 + (q << 2)]);
#pragma unroll
        for (int nt = 0; nt < 2; ++nt)
#pragma unroll
            for (int r = 0; r < 4; ++r) acc[ot][nt][r] += bb[r];
    }
    __syncthreads();   // elds dead; planes may overwrite

    // ---- P2/P3: chunked split-fp16 Gram. G = X X^T, o-chunks of 128. ----
    const int mi = w >> 1, ni = w & 1;
    f32x4 gacc = (f32x4){0.f, 0.f, 0.f, 0.f};
#pragma unroll
    for (int c = 0; c < 2; ++c) {
        if ((w >> 1) == c) {
            // spill this wave's 64 o-columns: b64 per (ot,nt,plane)
#pragma unroll
            for (int ot = 0; ot < 4; ++ot)
#pragma unroll
                for (int nt = 0; nt < 2; ++nt) {
                    int n  = nt * 16 + col;
                    int oc = (w & 1) * 64 + ot * 16 + (q << 2);
                    f16 hv[4], ev[4];
#pragma unroll
                    for (int r = 0; r < 4; ++r) {
                        float xv = acc[ot][nt][r];
                        hv[r] = (f16)xv;
                        ev[r] = (f16)(xv - (float)hv[r]);
                    }
                    int idx = xidx(n, oc);
                    *reinterpret_cast<f16x4*>(&xh[idx]) = *reinterpret_cast<f16x4*>(hv);
                    *reinterpret_cast<f16x4*>(&xe[idx]) = *reinterpret_cast<f16x4*>(ev);
                }
        }
        __syncthreads();
        // Gram partial over this chunk; wave w owns G tile (mi,ni).
#pragma unroll
        for (int ks = 0; ks < 4; ++ks) {
            int ra = xidx(mi * 16 + col, ks * 32 + (q << 3));
            f16x8 ha = *reinterpret_cast<const f16x8*>(&xh[ra]);
            f16x8 ea = *reinterpret_cast<const f16x8*>(&xe[ra]);
            f16x8 hb = ha, eb = ea;
            if (mi != ni) {
                int rb = xidx(ni * 16 + col, ks * 32 + (q << 3));
                hb = *reinterpret_cast<const f16x8*>(&xh[rb]);
                eb = *reinterpret_cast<const f16x8*>(&xe[rb]);
            }
            gacc = __builtin_amdgcn_mfma_f32_16x16x32_f16(ha, hb, gacc, 0, 0, 0);
            gacc = __builtin_amdgcn_mfma_f32_16x16x32_f16(ha, eb, gacc, 0, 0, 0);
            gacc = __builtin_amdgcn_mfma_f32_16x16x32_f16(ea, hb, gacc, 0, 0, 0);
        }
        if (c == 0) __syncthreads();   // reads done before round-1 overwrites
    }
#pragma unroll
    for (int r = 0; r < 4; ++r)
        glds[(mi * 16 + q * 4 + r) * 36 + ni * 16 + col] = gacc[r];
    __syncthreads();

    // ---- P4: wave 0 does ALL routing on the 32x32 Gram matrix ----
    float cval = 0.f, scale = 0.f, rn = 0.f;
    if (w == 0) {
        float dv = glds[n0 * 36 + n0];
        rn = rsqrtf(fmaxf(dv, 1e-24f));

        float g[32];
#pragma unroll
        for (int j8 = 0; j8 < 8; ++j8) {
            f32x4 gv = *reinterpret_cast<const f32x4*>(&glds[n0 * 36 + j8 * 4]);
#pragma unroll
            for (int r = 0; r < 4; ++r) g[j8 * 4 + r] = gv[r] * rn;
        }
#pragma unroll
        for (int j = 0; j < 32; ++j) g[j] *= rdlane(rn, j);

        for (int it = 0; it < 3; ++it) {
            float mx = bval;
            mx = fmaxf(mx, __shfl_xor(mx, 1));  mx = fmaxf(mx, __shfl_xor(mx, 2));
            mx = fmaxf(mx, __shfl_xor(mx, 4));  mx = fmaxf(mx, __shfl_xor(mx, 8));
            mx = fmaxf(mx, __shfl_xor(mx, 16));
            float ex = __expf(bval - mx);
            float sm = red32(ex);
            cval = ex * (32.0f / sm);
            float t0 = 0.f, t1 = 0.f;
#pragma unroll
            for (int j = 0; j < 32; j += 2) {
                t0 = fmaf(g[j],     rdlane(cval, j),     t0);
                t1 = fmaf(g[j + 1], rdlane(cval, j + 1), t1);
            }
            float t = t0 + t1;
            float sq = red32(cval * t);
            scale = sq / ((1.0f + sq) * sqrtf(sq + 1e-9f));
            if (it < 2) bval = fmaf(scale, t, bval);
        }

        if (l < 32) {
            cpls[l] = cval * rn;                                   // c'_n = c_n * rn_n
            out[(size_t)B_ * DOUT_ + (size_t)b * N_ + l] = cval;   // c_out
        }
        if (l == 0) *scls = scale;
    }
    __syncthreads();

    // ---- P6: s_o = sum_n c'_n x[n][o]; multi-value butterfly over the 16-col group.
    {
        float sc = *scls;
        float c0 = cpls[col];
        float c1 = cpls[16 + col];
        float cur[16];
#pragma unroll
        for (int ot = 0; ot < 4; ++ot)
#pragma unroll
            for (int r = 0; r < 4; ++r)
                cur[ot * 4 + r] = fmaf(c0, acc[ot][0][r], c1 * acc[ot][1][r]);

        // 4-stage butterfly: lane col ends with value index v == col,
        // summed over its 16-lane group. Static indices throughout.
        float k8[8], s8[8];
        {
            const bool hi = (col & 8) != 0;
#pragma unroll
            for (int i = 0; i < 8; ++i) {
                k8[i] = hi ? cur[i + 8] : cur[i];
                s8[i] = hi ? cur[i] : cur[i + 8];
            }
#pragma unroll
            for (int i = 0; i < 8; ++i) k8[i] += __shfl_xor(s8[i], 8);
        }
        float k4[4], s4[4];
        {
            const bool hi = (col & 4) != 0;
#pragma unroll
            for (int i = 0; i < 4; ++i) {
                k4[i] = hi ? k8[i + 4] : k8[i];
                s4[i] = hi ? k8[i] : k8[i + 4];
            }
#pragma unroll
            for (int i = 0; i < 4; ++i) k4[i] += __shfl_xor(s4[i], 4);
        }
        float k2[2], s2[2];
        {
            const bool hi = (col & 2) != 0;
#pragma unroll
            for (int i = 0; i < 2; ++i) {
                k2[i] = hi ? k4[i + 2] : k4[i];
                s2[i] = hi ? k4[i] : k4[i + 2];
            }
#pragma unroll
            for (int i = 0; i < 2; ++i) k2[i] += __shfl_xor(s2[i], 2);
        }
        float k1, s1;
        {
            const bool hi = (col & 1) != 0;
            k1 = hi ? k2[1] : k2[0];
            s1 = hi ? k2[0] : k2[1];
            k1 += __shfl_xor(s1, 1);
        }
        // lane (q,col) holds s[o], o = w*64 + (col>>2)*16 + q*4 + (col&3)
        int o = (col >> 2) * 16 + (q << 2) + (col & 3);
        out[(size_t)b * DOUT_ + w * 64 + o] = sc * k1;
    }
}

extern "C" void kernel_launch(void* const* d_in, const int* in_sizes, int n_in,
                              void* d_out, int out_size, void* d_ws, size_t ws_size,
                              hipStream_t stream) {
    const float* embeds  = (const float*)d_in[0];
    const float* weights = (const float*)d_in[1];
    const float* W       = (const float*)d_in[2];
    const float* bias    = (const float*)d_in[3];
    float* out = (float*)d_out;
    f16* wp = (f16*)d_ws;    // 64 KB of packed fp16 W

    prep_w<<<16, 256, 0, stream>>>(W, wp);
    dyr_main<<<B_, 256, 0, stream>>>(embeds, weights, wp, bias, out);
}